// Round 13
// baseline (451.923 us; speedup 1.0000x reference)
//
#include <hip/hip_runtime.h>
#include <hip/hip_bf16.h>
#include <cstdint>
#include <cstddef>

#define HDIM 4096
#define MROWS 8192
#define LN_EPS 1e-5f

typedef __bf16 bf16_t;
typedef __bf16 bf16x4_t __attribute__((ext_vector_type(4)));
typedef __bf16 bf16x8_t __attribute__((ext_vector_type(8)));
typedef float f32x4_t __attribute__((ext_vector_type(4)));
typedef float f32x16_t __attribute__((ext_vector_type(16)));

typedef const __attribute__((address_space(1))) void gvoid_t;
typedef __attribute__((address_space(3))) void lvoid_t;

__device__ __forceinline__ float softplus_f(float x) {
    return fmaxf(x, 0.f) + log1pf(expf(-fabsf(x)));
}

// ---- W = mu + softplus(rho)*eps  -> bf16 ----
__global__ __launch_bounds__(256) void wgen_kernel(
    const float* __restrict__ mu, const float* __restrict__ rho,
    const float* __restrict__ eps, bf16_t* __restrict__ W)
{
    int i = (blockIdx.x * 256 + threadIdx.x) * 4;
    float4 m = *(const float4*)(mu + i);
    float4 r = *(const float4*)(rho + i);
    float4 e = *(const float4*)(eps + i);
    bf16x4_t o;
    o[0] = (bf16_t)(m.x + softplus_f(r.x) * e.x);
    o[1] = (bf16_t)(m.y + softplus_f(r.y) * e.y);
    o[2] = (bf16_t)(m.z + softplus_f(r.z) * e.z);
    o[3] = (bf16_t)(m.w + softplus_f(r.w) * e.w);
    *(bf16x4_t*)(W + i) = o;
}

// ---- bias = b_mu + softplus(b_rho)*eps_b  (fp32) ----
__global__ __launch_bounds__(256) void biasgen_kernel(
    const float* __restrict__ mu, const float* __restrict__ rho,
    const float* __restrict__ eps, float* __restrict__ b)
{
    int i = blockIdx.x * 256 + threadIdx.x;
    b[i] = mu[i] + softplus_f(rho[i]) * eps[i];
}

// ---- LayerNorm per row of 4096, fp32 in -> bf16 out ----
__global__ __launch_bounds__(256) void ln_kernel(
    const float* __restrict__ x, const float* __restrict__ gamma,
    const float* __restrict__ beta, bf16_t* __restrict__ h)
{
    int row = blockIdx.x;
    const float* xr = x + (size_t)row * HDIM;
    int t = threadIdx.x;
    float4 v[4];
    float s = 0.f, s2 = 0.f;
#pragma unroll
    for (int j = 0; j < 4; ++j) {
        v[j] = *(const float4*)(xr + j * 1024 + t * 4);
        s  += v[j].x + v[j].y + v[j].z + v[j].w;
        s2 += v[j].x * v[j].x + v[j].y * v[j].y + v[j].z * v[j].z + v[j].w * v[j].w;
    }
#pragma unroll
    for (int off = 32; off > 0; off >>= 1) {
        s  += __shfl_down(s, off);
        s2 += __shfl_down(s2, off);
    }
    __shared__ float ps[4], ps2[4];
    if ((t & 63) == 0) { ps[t >> 6] = s; ps2[t >> 6] = s2; }
    __syncthreads();
    float tot  = ps[0] + ps[1] + ps[2] + ps[3];
    float tot2 = ps2[0] + ps2[1] + ps2[2] + ps2[3];
    float mean = tot * (1.f / HDIM);
    float var  = tot2 * (1.f / HDIM) - mean * mean;
    float rstd = rsqrtf(var + LN_EPS);
    bf16_t* hr = h + (size_t)row * HDIM;
#pragma unroll
    for (int j = 0; j < 4; ++j) {
        int c = j * 1024 + t * 4;
        float4 g  = *(const float4*)(gamma + c);
        float4 bb = *(const float4*)(beta + c);
        bf16x4_t o;
        o[0] = (bf16_t)((v[j].x - mean) * rstd * g.x + bb.x);
        o[1] = (bf16_t)((v[j].y - mean) * rstd * g.y + bb.y);
        o[2] = (bf16_t)((v[j].z - mean) * rstd * g.z + bb.z);
        o[3] = (bf16_t)((v[j].w - mean) * rstd * g.w + bb.w);
        *(bf16x4_t*)(hr + c) = o;
    }
}

__device__ __forceinline__ void gload_lds16(const bf16_t* g, const char* l) {
    __builtin_amdgcn_global_load_lds((gvoid_t*)g, (lvoid_t*)l, 16, 0, 0);
}

__device__ __forceinline__ bf16x8_t ds_read_b128_raw(const char* p) {
    f32x4_t r;
    asm volatile("ds_read_b128 %0, %1" : "=v"(r) : "v"((lvoid_t*)p));
    return __builtin_bit_cast(bf16x8_t, r);
}

// st-style LDS swizzle: flip byte bits 4,5 with bits 7,8. Involution,
// confined to 512B blocks.
__device__ __forceinline__ int swz(int x) { return x ^ ((x >> 3) & 0x30); }

// ---- GEMM: out[m][o] = x[m][o] + gelu( sum_k h[m][k]*W[o][k] + bias[o] ) ----
// r7 skeleton (256x256 tile, BK=32, 8 waves 2Mx4N, ring-4 LDS, counted-lgkm
// one-phase-lookahead, vmcnt(4)+1 barrier per K-tile) with 32x32x16 MFMA:
//  - per wave: 4(M) x 2(N) fragments of 32x32; 16 MFMA/K-tile (was 32)
//  - A-frag: row=lane&31, k=(lane>>5)*8+j (std CDNA blocked layout)
//  - C/D (HW-verified m74/m101): col=lane&31, row=(reg&3)+8*(reg>>2)+4*(lane>>5)
//  - per k-step (16) read-set: 4 A + 2 B ds_read_b128 => balanced lgkm(6)/(6)
//
// Counter ledger (per wave):
//  X(t): 6 ds outstanding (ks0 set). issue 6 (ks1) -> 12; lgkm(6) drains ks0
//    -> MFMA ks0 runs with 6 in flight. stage A(t+3).
//  Y(t): issue 6 (tile t+1 ks0) -> 12; lgkm(6) drains ks1 -> MFMA ks1 with
//    6 in flight. stage B(t+3). vmcnt(4) drains tile t+2's 4 stages (issued
//    iter t-1; t+2 read at Y(t+1) after barrier); keeps this iter's 4.
//  WAR: stages at t hit buf[(t-1)&3]; last reads (X(t-1) ks1) drained by
//    Y(t-1) lgkm(6) before its end barrier; stages issue after it.
//  Prologue: 12 gloads (tiles 0,1,2); vmcnt(4) drains tiles 0,1; tile 2
//    drained by end-Y(0)'s vmcnt(4), read at Y(1). Invariant holds.
__global__ __launch_bounds__(512, 2) void gemm_kernel(
    const bf16_t* __restrict__ A,   // [8192][4096] h (bf16)
    const bf16_t* __restrict__ B,   // [4096][4096] W (bf16, row=o col=k)
    const float* __restrict__ bias, // [4096]
    const float* __restrict__ xres, // [8192][4096] residual fp32
    float* __restrict__ out)        // [8192][4096]
{
    __shared__ char lds[131072];    // ring: buf b at b*32768; A at +0, B at +16KB

    const int tid  = threadIdx.x;
    const int lane = tid & 63, w = tid >> 6;
    const int fr32 = lane & 31, g2 = lane >> 5;
    const int wm = w >> 2, wn = w & 3;   // wave grid 2(M) x 4(N)

    // T1: bijective XCD swizzle (512 blocks, 512%8==0)
    int bid = blockIdx.x;
    int wg  = (bid & 7) * 64 + (bid >> 3);
    const int tileN = (wg & 15) * 256;
    const int tileM = (wg >> 4) * 256;

    // staging (r7-proven): linear LDS dest D = r*8192 + w*1024 + lane*16 per
    // region; LDS[D] holds linear-image value at S = swz(D).
    const bf16_t* srcA[2];
    const bf16_t* srcB[2];
    int ldstA[2], ldstB[2];
#pragma unroll
    for (int r = 0; r < 2; ++r) {
        int D = r * 8192 + w * 1024 + lane * 16;
        int S = swz(D);
        int row = S >> 6, colel = (S & 63) >> 1;
        srcA[r] = A + (size_t)(tileM + row) * HDIM + colel;
        srcB[r] = B + (size_t)(tileN + row) * HDIM + colel;
        ldstA[r] = r * 8192 + w * 1024;
        ldstB[r] = 16384 + r * 8192 + w * 1024;
    }

    // fragment ds_read offsets for k-step 0 (swizzled); k-step 1 = ^0x20
    // (L = row*64 + ks*32 + g2*16: bit5=ks, untouched by swz's source bits 7,8)
    int aoff[4], boff[2];
#pragma unroll
    for (int m = 0; m < 4; ++m)
        aoff[m] = swz((wm * 128 + m * 32 + fr32) * 64 + g2 * 16);
#pragma unroll
    for (int n = 0; n < 2; ++n)
        boff[n] = 16384 + swz((wn * 64 + n * 32 + fr32) * 64 + g2 * 16);

    f32x16_t acc[4][2] = {};
    const int NT = HDIM / 32;  // 128 K-tiles

    // register sets: P = cur ks0 (4A+2B); Q = cur ks1; R = next ks0
    bf16x8_t pa0, pa1, pa2, pa3, pv0, pv1;
    bf16x8_t qa0, qa1, qa2, qa3, qv0, qv1;
    bf16x8_t ra0, ra1, ra2, ra3, rv0, rv1;

#define STAGE_A(bb, kofs)                                        \
    do {                                                         \
        gload_lds16(srcA[0] + (kofs), &lds[(bb) + ldstA[0]]);    \
        gload_lds16(srcA[1] + (kofs), &lds[(bb) + ldstA[1]]);    \
    } while (0)
#define STAGE_B(bb, kofs)                                        \
    do {                                                         \
        gload_lds16(srcB[0] + (kofs), &lds[(bb) + ldstB[0]]);    \
        gload_lds16(srcB[1] + (kofs), &lds[(bb) + ldstB[1]]);    \
    } while (0)
#define SCHEDB __builtin_amdgcn_sched_barrier(0)
#define LGKM(n) do { asm volatile("s_waitcnt lgkmcnt(" #n ")" ::: "memory"); SCHEDB; } while (0)

    // RD6: read k-step KX (0 or 32) of tile tc into set (SA0..3, SV0..1)
#define RD6(tc, KX, SA, SV)                                           \
    do { const char* bp_ = &lds[((tc) & 3) * 32768];                  \
        SA##0 = ds_read_b128_raw(bp_ + (aoff[0] ^ (KX)));             \
        SA##1 = ds_read_b128_raw(bp_ + (aoff[1] ^ (KX)));             \
        SA##2 = ds_read_b128_raw(bp_ + (aoff[2] ^ (KX)));             \
        SA##3 = ds_read_b128_raw(bp_ + (aoff[3] ^ (KX)));             \
        SV##0 = ds_read_b128_raw(bp_ + (boff[0] ^ (KX)));             \
        SV##1 = ds_read_b128_raw(bp_ + (boff[1] ^ (KX))); } while (0)

#define MFMA8(A0, A1, A2, A3, V0, V1)                                           \
    acc[0][0] = __builtin_amdgcn_mfma_f32_32x32x16_bf16(A0, V0, acc[0][0], 0, 0, 0); \
    acc[0][1] = __builtin_amdgcn_mfma_f32_32x32x16_bf16(A0, V1, acc[0][1], 0, 0, 0); \
    acc[1][0] = __builtin_amdgcn_mfma_f32_32x32x16_bf16(A1, V0, acc[1][0], 0, 0, 0); \
    acc[1][1] = __builtin_amdgcn_mfma_f32_32x32x16_bf16(A1, V1, acc[1][1], 0, 0, 0); \
    acc[2][0] = __builtin_amdgcn_mfma_f32_32x32x16_bf16(A2, V0, acc[2][0], 0, 0, 0); \
    acc[2][1] = __builtin_amdgcn_mfma_f32_32x32x16_bf16(A2, V1, acc[2][1], 0, 0, 0); \
    acc[3][0] = __builtin_amdgcn_mfma_f32_32x32x16_bf16(A3, V0, acc[3][0], 0, 0, 0); \
    acc[3][1] = __builtin_amdgcn_mfma_f32_32x32x16_bf16(A3, V1, acc[3][1], 0, 0, 0);

    // One K-tile: current ks0 set (CA,CV); reads next tile's ks0 into (NA,NV).
#define KTILE(tc, CA, CV, NA, NV)                                     \
    do {                                                              \
        const int sb_ = (((tc) + 3) & 3) * 32768;                     \
        const int sk_ = (((tc) + 3) & (NT - 1)) * 32;                 \
        /* phase X: read ks1(t); stage A(t+3); MFMA ks0 */            \
        RD6(tc, 32, qa, qv);                                          \
        STAGE_A(sb_, sk_);                                            \
        SCHEDB;                                                       \
        LGKM(6);                                                      \
        __builtin_amdgcn_s_setprio(1);                                \
        MFMA8(CA##0, CA##1, CA##2, CA##3, CV##0, CV##1)               \
        __builtin_amdgcn_s_setprio(0);                                \
        SCHEDB;                                                       \
        /* phase Y: read ks0(t+1); stage B(t+3); MFMA ks1 */          \
        RD6((tc) + 1, 0, NA, NV);                                     \
        STAGE_B(sb_, sk_);                                            \
        SCHEDB;                                                       \
        LGKM(6);                                                      \
        __builtin_amdgcn_s_setprio(1);                                \
        MFMA8(qa0, qa1, qa2, qa3, qv0, qv1)                           \
        __builtin_amdgcn_s_setprio(0);                                \
        SCHEDB;                                                       \
        asm volatile("s_waitcnt vmcnt(4)" ::: "memory");              \
        __builtin_amdgcn_s_barrier();                                 \
        SCHEDB;                                                       \
    } while (0)

    // prologue: stage tiles 0,1,2; drain tiles 0,1 (keep A2,B2 = 4)
    STAGE_A(0, 0);      STAGE_B(0, 0);
    STAGE_A(32768, 32); STAGE_B(32768, 32);
    STAGE_A(65536, 64); STAGE_B(65536, 64);
    asm volatile("s_waitcnt vmcnt(4)" ::: "memory");
    __builtin_amdgcn_s_barrier();
    SCHEDB;
    RD6(0, 0, pa, pv);   // 6 ds outstanding: steady-state X-entry invariant
    SCHEDB;

#pragma unroll 1
    for (int t = 0; t < NT; t += 2) {
        KTILE(t,     pa, pv, ra, rv);   // even: cur=P, next=R
        KTILE(t + 1, ra, rv, pa, pv);   // odd:  cur=R, next=P
    }
#undef KTILE
#undef MFMA8
#undef RD6
#undef STAGE_A
#undef STAGE_B

    // epilogue: bias + exact GELU + residual, fp32 out
    // C/D 32x32 layout (m74/m101): col = lane&31,
    // row = (reg&3) + 8*(reg>>2) + 4*(lane>>5)
    const int col0 = tileN + wn * 64 + fr32;
    const int row0 = tileM + wm * 128 + g2 * 4;
#pragma unroll
    for (int n = 0; n < 2; ++n) {
        float bvv = bias[col0 + n * 32];
#pragma unroll
        for (int m = 0; m < 4; ++m) {
#pragma unroll
            for (int j = 0; j < 16; ++j) {
                int r = row0 + m * 32 + (j & 3) + 8 * (j >> 2);
                size_t idx = (size_t)r * HDIM + (col0 + n * 32);
                float v = acc[m][n][j] + bvv;
                float ge = 0.5f * v * (1.0f + erff(v * 0.70710678118654752f));
                out[idx] = xres[idx] + ge;
            }
        }
    }
}

extern "C" void kernel_launch(void* const* d_in, const int* in_sizes, int n_in,
                              void* d_out, int out_size, void* d_ws, size_t ws_size,
                              hipStream_t stream) {
    const float* x        = (const float*)d_in[0];
    const float* ln_gamma = (const float*)d_in[1];
    const float* ln_beta  = (const float*)d_in[2];
    const float* w_mu     = (const float*)d_in[3];
    const float* w_rho    = (const float*)d_in[4];
    const float* b_mu     = (const float*)d_in[5];
    const float* b_rho    = (const float*)d_in[6];
    const float* eps_w    = (const float*)d_in[7];
    const float* eps_b    = (const float*)d_in[8];
    float* out = (float*)d_out;

    char* ws = (char*)d_ws;
    bf16_t* h_bf16 = (bf16_t*)ws;                              // 64 MiB
    bf16_t* W_bf16 = (bf16_t*)(ws + 67108864);                 // 32 MiB
    float*  bias   = (float*)(ws + 67108864 + 33554432);       // 16 KiB

    wgen_kernel<<<16384, 256, 0, stream>>>(w_mu, w_rho, eps_w, W_bf16);
    biasgen_kernel<<<16, 256, 0, stream>>>(b_mu, b_rho, eps_b, bias);
    ln_kernel<<<MROWS, 256, 0, stream>>>(x, ln_gamma, ln_beta, h_bf16);
    gemm_kernel<<<512, 512, 0, stream>>>(h_bf16, W_bf16, bias, x, out);
}

// Round 14
// 425.189 us; speedup vs baseline: 1.0629x; 1.0629x over previous
//
#include <hip/hip_runtime.h>
#include <hip/hip_bf16.h>
#include <cstdint>
#include <cstddef>

#define HDIM 4096
#define MROWS 8192
#define LN_EPS 1e-5f

typedef __bf16 bf16_t;
typedef __bf16 bf16x4_t __attribute__((ext_vector_type(4)));
typedef __bf16 bf16x8_t __attribute__((ext_vector_type(8)));
typedef float f32x4_t __attribute__((ext_vector_type(4)));

typedef const __attribute__((address_space(1))) void gvoid_t;
typedef __attribute__((address_space(3))) void lvoid_t;

__device__ __forceinline__ float softplus_f(float x) {
    return fmaxf(x, 0.f) + log1pf(expf(-fabsf(x)));
}

// ---- W = mu + softplus(rho)*eps  -> bf16 ----
__global__ __launch_bounds__(256) void wgen_kernel(
    const float* __restrict__ mu, const float* __restrict__ rho,
    const float* __restrict__ eps, bf16_t* __restrict__ W)
{
    int i = (blockIdx.x * 256 + threadIdx.x) * 4;
    float4 m = *(const float4*)(mu + i);
    float4 r = *(const float4*)(rho + i);
    float4 e = *(const float4*)(eps + i);
    bf16x4_t o;
    o[0] = (bf16_t)(m.x + softplus_f(r.x) * e.x);
    o[1] = (bf16_t)(m.y + softplus_f(r.y) * e.y);
    o[2] = (bf16_t)(m.z + softplus_f(r.z) * e.z);
    o[3] = (bf16_t)(m.w + softplus_f(r.w) * e.w);
    *(bf16x4_t*)(W + i) = o;
}

// ---- bias = b_mu + softplus(b_rho)*eps_b  (fp32) ----
__global__ __launch_bounds__(256) void biasgen_kernel(
    const float* __restrict__ mu, const float* __restrict__ rho,
    const float* __restrict__ eps, float* __restrict__ b)
{
    int i = blockIdx.x * 256 + threadIdx.x;
    b[i] = mu[i] + softplus_f(rho[i]) * eps[i];
}

// ---- LayerNorm per row of 4096, fp32 in -> bf16 out ----
__global__ __launch_bounds__(256) void ln_kernel(
    const float* __restrict__ x, const float* __restrict__ gamma,
    const float* __restrict__ beta, bf16_t* __restrict__ h)
{
    int row = blockIdx.x;
    const float* xr = x + (size_t)row * HDIM;
    int t = threadIdx.x;
    float4 v[4];
    float s = 0.f, s2 = 0.f;
#pragma unroll
    for (int j = 0; j < 4; ++j) {
        v[j] = *(const float4*)(xr + j * 1024 + t * 4);
        s  += v[j].x + v[j].y + v[j].z + v[j].w;
        s2 += v[j].x * v[j].x + v[j].y * v[j].y + v[j].z * v[j].z + v[j].w * v[j].w;
    }
#pragma unroll
    for (int off = 32; off > 0; off >>= 1) {
        s  += __shfl_down(s, off);
        s2 += __shfl_down(s2, off);
    }
    __shared__ float ps[4], ps2[4];
    if ((t & 63) == 0) { ps[t >> 6] = s; ps2[t >> 6] = s2; }
    __syncthreads();
    float tot  = ps[0] + ps[1] + ps[2] + ps[3];
    float tot2 = ps2[0] + ps2[1] + ps2[2] + ps2[3];
    float mean = tot * (1.f / HDIM);
    float var  = tot2 * (1.f / HDIM) - mean * mean;
    float rstd = rsqrtf(var + LN_EPS);
    bf16_t* hr = h + (size_t)row * HDIM;
#pragma unroll
    for (int j = 0; j < 4; ++j) {
        int c = j * 1024 + t * 4;
        float4 g  = *(const float4*)(gamma + c);
        float4 bb = *(const float4*)(beta + c);
        bf16x4_t o;
        o[0] = (bf16_t)((v[j].x - mean) * rstd * g.x + bb.x);
        o[1] = (bf16_t)((v[j].y - mean) * rstd * g.y + bb.y);
        o[2] = (bf16_t)((v[j].z - mean) * rstd * g.z + bb.z);
        o[3] = (bf16_t)((v[j].w - mean) * rstd * g.w + bb.w);
        *(bf16x4_t*)(hr + c) = o;
    }
}

__device__ __forceinline__ void gload_lds16(const bf16_t* g, const char* l) {
    __builtin_amdgcn_global_load_lds((gvoid_t*)g, (lvoid_t*)l, 16, 0, 0);
}

// Inline-asm LDS read: keeps wait insertion in OUR hands (counted lgkm).
__device__ __forceinline__ bf16x8_t ds_read_b128_raw(const char* p) {
    f32x4_t r;
    asm volatile("ds_read_b128 %0, %1" : "=v"(r) : "v"((lvoid_t*)p));
    return __builtin_bit_cast(bf16x8_t, r);
}

// st-style LDS swizzle: flip byte bits 4,5 with bits 7,8. Involution,
// confined to 512B blocks.
__device__ __forceinline__ int swz(int x) { return x ^ ((x >> 3) & 0x30); }

// ---- GEMM: out[m][o] = x[m][o] + gelu( sum_k h[m][k]*W[o][k] + bias[o] ) ----
// r7 skeleton (256x256, BK=32, 8 waves 2Mx4N, ring-4, 16x16x32 MFMA,
// one-phase-lookahead, vmcnt(4)+1 barrier/K-tile) + STEPPED lgkm waits:
// each monolithic lgkm is split into 4 stepped waits interleaved with the
// 4-MFMA sub-blocks, so the first MFMAs start as soon as their operands'
// reads land and the remaining LDS service hides under MFMA issue.
//
// Read-issue order per set: B (pv) FIRST, then A (pa) — so the first
// consumable group (pv0-3 + pa0) is the oldest 5 of the issue window.
//
// Wait-count proof (ds ops only count in lgkm; gloads are vmcnt):
//  X(t) entry: 8 outstanding [pv0-3, pa0-3]; RDQ issues qa0-3 -> 12.
//    CL(pa0): needs reads 1-5   -> lgkm(7);  CL(pa1): read 6 -> lgkm(6);
//    CL(pa2): read 7 -> lgkm(5); CL(pa3): read 8 -> lgkm(4).
//    Final state lgkm(4) == r7's X  -> identical invariants.
//  Y(t) entry: 4 outstanding [qa0-3]; RDN issues nv0-3,na0-3 -> 12.
//    CL(qa0): oldest -> lgkm(11); qa1 -> lgkm(10); qa2 -> lgkm(9);
//    qa3 -> lgkm(8).  Final state lgkm(8) == r7's Y -> identical WAR
//    guarantee (buf[(t-1)&3]'s last reads drained before end barrier).
//  vmcnt(4)+barrier per K-tile: unchanged from r7 (ledger in r7 comments).
__global__ __launch_bounds__(512, 2) void gemm_kernel(
    const bf16_t* __restrict__ A,   // [8192][4096] h (bf16)
    const bf16_t* __restrict__ B,   // [4096][4096] W (bf16, row=o col=k)
    const float* __restrict__ bias, // [4096]
    const float* __restrict__ xres, // [8192][4096] residual fp32
    float* __restrict__ out)        // [8192][4096]
{
    __shared__ char lds[131072];    // ring: buf b at b*32768; A at +0, B at +16KB

    const int tid  = threadIdx.x;
    const int lane = tid & 63, w = tid >> 6;
    const int g = lane >> 4, fr = lane & 15;
    const int wm = w >> 2, wn = w & 3;   // wave grid 2(M) x 4(N)

    // T1: bijective XCD swizzle (512 blocks, 512%8==0)
    int bid = blockIdx.x;
    int wg  = (bid & 7) * 64 + (bid >> 3);
    const int tileN = (wg & 15) * 256;
    const int tileM = (wg >> 4) * 256;

    // staging: linear LDS dest D = r*8192 + w*1024 + lane*16 per region;
    // LDS[D] holds linear-image value at S = swz(D).
    const bf16_t* srcA[2];
    const bf16_t* srcB[2];
    int ldstA[2], ldstB[2];
#pragma unroll
    for (int r = 0; r < 2; ++r) {
        int D = r * 8192 + w * 1024 + lane * 16;
        int S = swz(D);
        int row = S >> 6, colel = (S & 63) >> 1;
        srcA[r] = A + (size_t)(tileM + row) * HDIM + colel;
        srcB[r] = B + (size_t)(tileN + row) * HDIM + colel;
        ldstA[r] = r * 8192 + w * 1024;
        ldstB[r] = 16384 + r * 8192 + w * 1024;
    }

    // fragment ds_read offsets (swizzled, relative to buffer base)
    int aoff[8], boff[4];
#pragma unroll
    for (int m = 0; m < 8; ++m)
        aoff[m] = swz(wm * 8192 + m * 1024 + fr * 64 + g * 16);
#pragma unroll
    for (int n = 0; n < 4; ++n)
        boff[n] = 16384 + swz(wn * 4096 + n * 1024 + fr * 64 + g * 16);

    f32x4_t acc[8][4] = {};
    const int NT = HDIM / 32;  // 128 K-tiles

    // register sets: P = cur low-A + B; Q = cur high-A; R = next low-A + B
    bf16x8_t pa0, pa1, pa2, pa3, pv0, pv1, pv2, pv3;
    bf16x8_t qa0, qa1, qa2, qa3;
    bf16x8_t ra0, ra1, ra2, ra3, rv0, rv1, rv2, rv3;

#define STAGE_A(bb, kofs)                                        \
    do {                                                         \
        gload_lds16(srcA[0] + (kofs), &lds[(bb) + ldstA[0]]);    \
        gload_lds16(srcA[1] + (kofs), &lds[(bb) + ldstA[1]]);    \
    } while (0)
#define STAGE_B(bb, kofs)                                        \
    do {                                                         \
        gload_lds16(srcB[0] + (kofs), &lds[(bb) + ldstB[0]]);    \
        gload_lds16(srcB[1] + (kofs), &lds[(bb) + ldstB[1]]);    \
    } while (0)
#define CL(AF, V, R)                                                            \
    acc[R][0] = __builtin_amdgcn_mfma_f32_16x16x32_bf16(AF, V##0, acc[R][0], 0, 0, 0); \
    acc[R][1] = __builtin_amdgcn_mfma_f32_16x16x32_bf16(AF, V##1, acc[R][1], 0, 0, 0); \
    acc[R][2] = __builtin_amdgcn_mfma_f32_16x16x32_bf16(AF, V##2, acc[R][2], 0, 0, 0); \
    acc[R][3] = __builtin_amdgcn_mfma_f32_16x16x32_bf16(AF, V##3, acc[R][3], 0, 0, 0);
#define SCHEDB __builtin_amdgcn_sched_barrier(0)
#define LGKM(n) do { asm volatile("s_waitcnt lgkmcnt(" #n ")" ::: "memory"); SCHEDB; } while (0)

    // RDQ: 4 high-A reads of tile tc.
#define RDQ(tc)                                                       \
    do { const char* bp_ = &lds[((tc) & 3) * 32768];                  \
        qa0 = ds_read_b128_raw(bp_ + aoff[4]);                        \
        qa1 = ds_read_b128_raw(bp_ + aoff[5]);                        \
        qa2 = ds_read_b128_raw(bp_ + aoff[6]);                        \
        qa3 = ds_read_b128_raw(bp_ + aoff[7]); } while (0)
    // RDN: 8 reads of tile tc — B (SV) FIRST, then low-A (SA).
#define RDN(tc, SA, SV)                                               \
    do { const char* bp_ = &lds[((tc) & 3) * 32768];                  \
        SV##0 = ds_read_b128_raw(bp_ + boff[0]);                      \
        SV##1 = ds_read_b128_raw(bp_ + boff[1]);                      \
        SV##2 = ds_read_b128_raw(bp_ + boff[2]);                      \
        SV##3 = ds_read_b128_raw(bp_ + boff[3]);                      \
        SA##0 = ds_read_b128_raw(bp_ + aoff[0]);                      \
        SA##1 = ds_read_b128_raw(bp_ + aoff[1]);                      \
        SA##2 = ds_read_b128_raw(bp_ + aoff[2]);                      \
        SA##3 = ds_read_b128_raw(bp_ + aoff[3]); } while (0)

    // One K-tile with stepped lgkm waits.
#define KTILE(tc, CA, CV, NA, NV)                                     \
    do {                                                              \
        const int sb_ = (((tc) + 3) & 3) * 32768;                     \
        const int sk_ = (((tc) + 3) & (NT - 1)) * 32;                 \
        /* phase X: issue qa(t); stage A(t+3); stepped MFMA on CA/CV */ \
        RDQ(tc);                                                      \
        STAGE_A(sb_, sk_);                                            \
        SCHEDB;                                                       \
        __builtin_amdgcn_s_setprio(1);                                \
        LGKM(7);  CL(CA##0, CV, 0)                                    \
        LGKM(6);  CL(CA##1, CV, 1)                                    \
        LGKM(5);  CL(CA##2, CV, 2)                                    \
        LGKM(4);  CL(CA##3, CV, 3)                                    \
        __builtin_amdgcn_s_setprio(0);                                \
        SCHEDB;                                                       \
        /* phase Y: issue next tile's NV,NA; stage B(t+3); stepped MFMA qa */ \
        RDN((tc) + 1, NA, NV);                                        \
        STAGE_B(sb_, sk_);                                            \
        SCHEDB;                                                       \
        __builtin_amdgcn_s_setprio(1);                                \
        LGKM(11); CL(qa0, CV, 4)                                      \
        LGKM(10); CL(qa1, CV, 5)                                      \
        LGKM(9);  CL(qa2, CV, 6)                                      \
        LGKM(8);  CL(qa3, CV, 7)                                      \
        __builtin_amdgcn_s_setprio(0);                                \
        SCHEDB;                                                       \
        asm volatile("s_waitcnt vmcnt(4)" ::: "memory");              \
        __builtin_amdgcn_s_barrier();                                 \
        SCHEDB;                                                       \
    } while (0)

    // prologue: stage tiles 0,1,2; drain tiles 0,1 (keep A2,B2 = 4)
    STAGE_A(0, 0);      STAGE_B(0, 0);
    STAGE_A(32768, 32); STAGE_B(32768, 32);
    STAGE_A(65536, 64); STAGE_B(65536, 64);
    asm volatile("s_waitcnt vmcnt(4)" ::: "memory");
    __builtin_amdgcn_s_barrier();
    SCHEDB;
    RDN(0, pa, pv);   // 8 ds outstanding: steady-state X-entry invariant
    SCHEDB;

#pragma unroll 1
    for (int t = 0; t < NT; t += 2) {
        KTILE(t,     pa, pv, ra, rv);   // even: cur=P, next=R
        KTILE(t + 1, ra, rv, pa, pv);   // odd:  cur=R, next=P
    }
#undef KTILE
#undef RDQ
#undef RDN
#undef STAGE_A
#undef STAGE_B

    // epilogue: bias + exact GELU + residual, fp32 out
    // C/D layout: col = lane&15, row = (lane>>4)*4 + j
    const int col0 = tileN + wn * 64 + fr;
    const int row0 = tileM + wm * 128 + g * 4;
#pragma unroll
    for (int n = 0; n < 4; ++n) {
        float bvv = bias[col0 + n * 16];
#pragma unroll
        for (int m = 0; m < 8; ++m) {
#pragma unroll
            for (int j = 0; j < 4; ++j) {
                size_t idx = (size_t)(row0 + m * 16 + j) * HDIM + (col0 + n * 16);
                float v = acc[m][n][j] + bvv;
                float ge = 0.5f * v * (1.0f + erff(v * 0.70710678118654752f));
                out[idx] = xres[idx] + ge;
            }
        }
    }
}

extern "C" void kernel_launch(void* const* d_in, const int* in_sizes, int n_in,
                              void* d_out, int out_size, void* d_ws, size_t ws_size,
                              hipStream_t stream) {
    const float* x        = (const float*)d_in[0];
    const float* ln_gamma = (const float*)d_in[1];
    const float* ln_beta  = (const float*)d_in[2];
    const float* w_mu     = (const float*)d_in[3];
    const float* w_rho    = (const float*)d_in[4];
    const float* b_mu     = (const float*)d_in[5];
    const float* b_rho    = (const float*)d_in[6];
    const float* eps_w    = (const float*)d_in[7];
    const float* eps_b    = (const float*)d_in[8];
    float* out = (float*)d_out;

    char* ws = (char*)d_ws;
    bf16_t* h_bf16 = (bf16_t*)ws;                              // 64 MiB
    bf16_t* W_bf16 = (bf16_t*)(ws + 67108864);                 // 32 MiB
    float*  bias   = (float*)(ws + 67108864 + 33554432);       // 16 KiB

    wgen_kernel<<<16384, 256, 0, stream>>>(w_mu, w_rho, eps_w, W_bf16);
    biasgen_kernel<<<16, 256, 0, stream>>>(b_mu, b_rho, eps_b, bias);
    ln_kernel<<<MROWS, 256, 0, stream>>>(x, ln_gamma, ln_beta, h_bf16);
    gemm_kernel<<<512, 512, 0, stream>>>(h_bf16, W_bf16, bias, x, out);
}